// Round 3
// baseline (1045.786 us; speedup 1.0000x reference)
//
#include <hip/hip_runtime.h>

#define FIN 512
#define FHID 16
#define FOUT 40
#define NBMAX 4096   // max buckets (32 nodes each -> n <= 131072)

// ---------------- degree count ----------------

__global__ void k_count(const int* __restrict__ dst, int* __restrict__ cnt, int E) {
    int e = blockIdx.x * blockDim.x + threadIdx.x;
    if (e < E) atomicAdd(&cnt[dst[e]], 1);
}

// ---------------- bucket sums + dinv ----------------
// bucket b covers nodes [b*32, b*32+32); bcnt[b] = sum of cnt; dinv = rsqrt(cnt+1)

__global__ void k_bsum(const int* __restrict__ cnt, int* __restrict__ bcnt,
                       float* __restrict__ dinv, int n, int NB) {
    int b = blockIdx.x * blockDim.x + threadIdx.x;
    if (b >= NBMAX) return;
    if (b >= NB) { bcnt[b] = 0; return; }
    int base = b << 5;
    int lim = n - base; if (lim > 32) lim = 32;
    int s = 0;
    if (lim == 32) {
        const int4* cp = reinterpret_cast<const int4*>(cnt + base);
        float4* dp = reinterpret_cast<float4*>(dinv + base);
#pragma unroll
        for (int j = 0; j < 8; ++j) {
            int4 v = cp[j];
            s += v.x + v.y + v.z + v.w;
            float4 dv;
            dv.x = rsqrtf((float)(v.x + 1));
            dv.y = rsqrtf((float)(v.y + 1));
            dv.z = rsqrtf((float)(v.z + 1));
            dv.w = rsqrtf((float)(v.w + 1));
            dp[j] = dv;
        }
    } else {
        for (int i = 0; i < lim; ++i) {
            int c = cnt[base + i];
            s += c;
            dinv[base + i] = rsqrtf((float)(c + 1));
        }
    }
    bcnt[b] = s;
}

// ---------------- scan 4096 bucket counts (1 block, 4/thread via int4) ----------------

__global__ __launch_bounds__(1024) void k_scan1(const int* __restrict__ bcnt,
                                                int* __restrict__ boff,
                                                int* __restrict__ cursor) {
    __shared__ int part[1024];
    int t = threadIdx.x;
    int4 c4 = reinterpret_cast<const int4*>(bcnt)[t];
    int s = c4.x + c4.y + c4.z + c4.w;
    part[t] = s;
    __syncthreads();
    for (int off = 1; off < 1024; off <<= 1) {
        int v = (t >= off) ? part[t - off] : 0;
        __syncthreads();
        part[t] += v;
        __syncthreads();
    }
    int base = t ? part[t - 1] : 0;
    int4 o;
    o.x = base;
    o.y = o.x + c4.x;
    o.z = o.y + c4.y;
    o.w = o.z + c4.z;
    reinterpret_cast<int4*>(boff)[t] = o;
    reinterpret_cast<int4*>(cursor)[t] = o;
}

// ---------------- bucket fill: sorted[p] = (dstloc << sb) | src ----------------

__global__ void k_fill(const int* __restrict__ src, const int* __restrict__ dst,
                       int* __restrict__ cursor, unsigned* __restrict__ sorted,
                       int E, int sb) {
    int e = blockIdx.x * blockDim.x + threadIdx.x;
    if (e >= E) return;
    int s = src[e], d = dst[e];
    int p = atomicAdd(&cursor[d >> 5], 1);
    sorted[p] = ((unsigned)(d & 31) << sb) | (unsigned)s;
}

// ---------------- layer 1 GEMM: g = (x @ W1) * dinv ----------------
// W1 rows are wave-uniform -> scalar loads (s_load_dwordx16); x streamed per-thread.

__global__ __launch_bounds__(64) void k_gemm1(const float* __restrict__ x,
                                              const float* __restrict__ W1,
                                              const float* __restrict__ dinv,
                                              float* __restrict__ g, int n) {
    int row = blockIdx.x * 64 + threadIdx.x;
    int r = row < n ? row : 0;
    const float4* xr = reinterpret_cast<const float4*>(x + (size_t)r * FIN);

    float acc[FHID];
#pragma unroll
    for (int o = 0; o < FHID; ++o) acc[o] = 0.0f;

#pragma unroll 1
    for (int kt = 0; kt < FIN / 32; ++kt) {
        float4 xv[8];
#pragma unroll
        for (int j = 0; j < 8; ++j) xv[j] = xr[kt * 8 + j];
#pragma unroll
        for (int j = 0; j < 8; ++j) {
#pragma unroll
            for (int q = 0; q < 4; ++q) {
                float xs = (&xv[j].x)[q];
                const float* wrow = W1 + (kt * 32 + j * 4 + q) * FHID;  // uniform addr
#pragma unroll
                for (int o = 0; o < FHID; ++o) acc[o] = fmaf(xs, wrow[o], acc[o]);
            }
        }
    }

    if (row < n) {
        float dv = dinv[row];
        float4* gp = reinterpret_cast<float4*>(g + (size_t)row * FHID);
#pragma unroll
        for (int q = 0; q < FHID / 4; ++q) {
            float4 v;
            v.x = acc[4 * q + 0] * dv;
            v.y = acc[4 * q + 1] * dv;
            v.z = acc[4 * q + 2] * dv;
            v.w = acc[4 * q + 3] * dv;
            gp[q] = v;
        }
    }
}

// ---------------- bucket aggregate: one block per 32-node bucket, LDS atomics --------
// LAYER 1: out = relu(sum*dinv + b1) * dinv ; LAYER 2: out = sum*dinv

template <int LAYER>
__global__ __launch_bounds__(256) void k_agg(const int* __restrict__ boff,
                                             const unsigned* __restrict__ sorted,
                                             const float* __restrict__ gin,
                                             const float* __restrict__ dinv,
                                             const float* __restrict__ b1,
                                             float* __restrict__ gout, int n, int sb) {
    int b = blockIdx.x;
    int base = b << 5;
    __shared__ float acc[32 * FHID];  // 2 KiB
    int t = threadIdx.x;

    // init with self-loop message g[node]
#pragma unroll
    for (int i = t; i < 32 * FHID; i += 256) {
        int nd = base + (i >> 4);
        acc[i] = (nd < n) ? gin[(size_t)nd * FHID + (i & 15)] : 0.0f;
    }
    __syncthreads();

    unsigned smask = (1u << sb) - 1u;
    int c = t & 15, eg = t >> 4;  // 16 edge-groups x 16 channels
    int beg = boff[b], end = boff[b + 1];
    for (int i = beg + eg; i < end; i += 16) {
        unsigned v = sorted[i];
        int s = (int)(v & smask);
        int loc = (int)(v >> sb);
        atomicAdd(&acc[(loc << 4) + c], gin[(size_t)s * FHID + c]);
    }
    __syncthreads();

#pragma unroll
    for (int i = t; i < 32 * FHID; i += 256) {
        int nd = base + (i >> 4);
        if (nd < n) {
            float dv = dinv[nd];
            float v = acc[i] * dv;
            if (LAYER == 1) v = fmaxf(v + b1[i & 15], 0.0f) * dv;
            gout[(size_t)nd * FHID + (i & 15)] = v;
        }
    }
}

// ---------------- finish layer 2: out = log_softmax(q @ W2 + b2) ----------------

__global__ __launch_bounds__(256) void k_finish2(const float* __restrict__ q_in,
                                                 const float* __restrict__ W2,
                                                 const float* __restrict__ b2,
                                                 float* __restrict__ out, int n) {
    __shared__ float Wl[FHID * FOUT];
    __shared__ float bl[FOUT];
    for (int i = threadIdx.x; i < FHID * FOUT; i += 256) Wl[i] = W2[i];
    for (int i = threadIdx.x; i < FOUT; i += 256) bl[i] = b2[i];
    __syncthreads();

    int row = blockIdx.x * 256 + threadIdx.x;
    if (row >= n) return;

    float q[FHID];
    const float4* ap = reinterpret_cast<const float4*>(q_in + (size_t)row * FHID);
#pragma unroll
    for (int t = 0; t < FHID / 4; ++t) {
        float4 v = ap[t];
        q[4 * t + 0] = v.x; q[4 * t + 1] = v.y; q[4 * t + 2] = v.z; q[4 * t + 3] = v.w;
    }

    float acc[FOUT];
#pragma unroll
    for (int o = 0; o < FOUT; ++o) acc[o] = bl[o];
#pragma unroll
    for (int k = 0; k < FHID; ++k) {
        float qs = q[k];
        const float* wrow = &Wl[k * FOUT];
#pragma unroll
        for (int o = 0; o < FOUT; ++o) acc[o] = fmaf(qs, wrow[o], acc[o]);
    }

    float m = acc[0];
#pragma unroll
    for (int o = 1; o < FOUT; ++o) m = fmaxf(m, acc[o]);
    float ssum = 0.0f;
#pragma unroll
    for (int o = 0; o < FOUT; ++o) ssum += expf(acc[o] - m);
    float lse = m + logf(ssum);

    float4* op = reinterpret_cast<float4*>(out + (size_t)row * FOUT);
#pragma unroll
    for (int t = 0; t < FOUT / 4; ++t) {
        float4 v;
        v.x = acc[4 * t + 0] - lse;
        v.y = acc[4 * t + 1] - lse;
        v.z = acc[4 * t + 2] - lse;
        v.w = acc[4 * t + 3] - lse;
        op[t] = v;
    }
}

// ---------------- launch ----------------

extern "C" void kernel_launch(void* const* d_in, const int* in_sizes, int n_in,
                              void* d_out, int out_size, void* d_ws, size_t ws_size,
                              hipStream_t stream) {
    const float* x  = (const float*)d_in[0];
    const int*   ei = (const int*)d_in[1];
    const float* W1 = (const float*)d_in[2];
    const float* b1 = (const float*)d_in[3];
    const float* W2 = (const float*)d_in[4];
    const float* b2 = (const float*)d_in[5];

    const int fh = in_sizes[3];              // 16
    const int fi = in_sizes[2] / fh;         // 512
    const int n  = in_sizes[0] / fi;         // 100000
    const int E  = in_sizes[1] / 2;          // 3200000
    (void)n_in; (void)out_size; (void)ws_size;

    const int* src = ei;
    const int* dst = ei + E;

    int sb = 32 - __builtin_clz((unsigned)(n - 1));  // bits for src id (17)
    const int NB = (n + 31) >> 5;                    // 3125 buckets of 32 nodes

    // workspace layout (all 16B-aligned)
    char* w = (char*)d_ws;
    unsigned* sorted = (unsigned*)w;   w += (size_t)E * 4;
    int*   cnt       = (int*)w;        w += (size_t)n * 4;
    int*   bcnt      = (int*)w;        w += (size_t)NBMAX * 4;
    int*   boff      = (int*)w;        w += (size_t)NBMAX * 4;
    int*   cursor    = (int*)w;        w += (size_t)NBMAX * 4;
    float* dinv      = (float*)w;      w += (size_t)n * 4;
    float* g         = (float*)w;      w += (size_t)n * FHID * 4;
    float* p         = (float*)w;

    float* out = (float*)d_out;

    const int TB = 256;
    const int nb_e = (E + TB - 1) / TB;
    const int nb_n = (n + TB - 1) / TB;

    hipMemsetAsync(cnt, 0, (size_t)n * 4, stream);
    k_count<<<nb_e, TB, 0, stream>>>(dst, cnt, E);
    k_bsum<<<NBMAX / TB, TB, 0, stream>>>(cnt, bcnt, dinv, n, NB);
    k_scan1<<<1, 1024, 0, stream>>>(bcnt, boff, cursor);
    k_fill<<<nb_e, TB, 0, stream>>>(src, dst, cursor, sorted, E, sb);

    k_gemm1<<<(n + 63) / 64, 64, 0, stream>>>(x, W1, dinv, g, n);
    k_agg<1><<<NB, TB, 0, stream>>>(boff, sorted, g, dinv, b1, p, n, sb);
    k_agg<2><<<NB, TB, 0, stream>>>(boff, sorted, p, dinv, b1, g, n, sb);
    k_finish2<<<nb_n, TB, 0, stream>>>(g, W2, b2, out, n);
}

// Round 4
// 1018.153 us; speedup vs baseline: 1.0271x; 1.0271x over previous
//
#include <hip/hip_runtime.h>
#include <hip/hip_fp16.h>

#define FIN 512
#define FHID 16
#define FOUT 40
#define NBMAX 4096   // max buckets of 32 nodes -> n <= 131072

// ---------------- degree count ----------------

__global__ void k_count(const int* __restrict__ dst, int* __restrict__ cnt, int E) {
    int e = blockIdx.x * blockDim.x + threadIdx.x;
    if (e < E) atomicAdd(&cnt[dst[e]], 1);
}

// ---------------- bucket sums + dinv ----------------

__global__ void k_bsum(const int* __restrict__ cnt, int* __restrict__ bcnt,
                       float* __restrict__ dinv, int n, int NB) {
    int b = blockIdx.x * blockDim.x + threadIdx.x;
    if (b >= NBMAX) return;
    if (b >= NB) { bcnt[b] = 0; return; }
    int base = b << 5;
    int lim = n - base; if (lim > 32) lim = 32;
    int s = 0;
    if (lim == 32) {
        const int4* cp = reinterpret_cast<const int4*>(cnt + base);
        float4* dp = reinterpret_cast<float4*>(dinv + base);
#pragma unroll
        for (int j = 0; j < 8; ++j) {
            int4 v = cp[j];
            s += v.x + v.y + v.z + v.w;
            float4 dv;
            dv.x = rsqrtf((float)(v.x + 1));
            dv.y = rsqrtf((float)(v.y + 1));
            dv.z = rsqrtf((float)(v.z + 1));
            dv.w = rsqrtf((float)(v.w + 1));
            dp[j] = dv;
        }
    } else {
        for (int i = 0; i < lim; ++i) {
            int c = cnt[base + i];
            s += c;
            dinv[base + i] = rsqrtf((float)(c + 1));
        }
    }
    bcnt[b] = s;
}

// ---------------- scan 4096 bucket counts ----------------

__global__ __launch_bounds__(1024) void k_scan1(const int* __restrict__ bcnt,
                                                int* __restrict__ boff,
                                                int* __restrict__ cursor) {
    __shared__ int part[1024];
    int t = threadIdx.x;
    int4 c4 = reinterpret_cast<const int4*>(bcnt)[t];
    int s = c4.x + c4.y + c4.z + c4.w;
    part[t] = s;
    __syncthreads();
    for (int off = 1; off < 1024; off <<= 1) {
        int v = (t >= off) ? part[t - off] : 0;
        __syncthreads();
        part[t] += v;
        __syncthreads();
    }
    int base = t ? part[t - 1] : 0;
    int4 o;
    o.x = base;
    o.y = o.x + c4.x;
    o.z = o.y + c4.y;
    o.w = o.z + c4.z;
    reinterpret_cast<int4*>(boff)[t] = o;
    reinterpret_cast<int4*>(cursor)[t] = o;
}

// ---------------- bucket fill ----------------

__global__ void k_fill(const int* __restrict__ src, const int* __restrict__ dst,
                       int* __restrict__ cursor, unsigned* __restrict__ sorted,
                       int E, int sb) {
    int e = blockIdx.x * blockDim.x + threadIdx.x;
    if (e >= E) return;
    int s = src[e], d = dst[e];
    int p = atomicAdd(&cursor[d >> 5], 1);
    sorted[p] = ((unsigned)(d & 31) << sb) | (unsigned)s;
}

// ---------------- layer 1 GEMM: g = fp16((x @ W1) * dinv) ----------------

__global__ __launch_bounds__(256) void k_gemm1(const float* __restrict__ x,
                                               const float* __restrict__ W1,
                                               const float* __restrict__ dinv,
                                               __half* __restrict__ g, int n) {
    __shared__ float Wl[FIN * FHID];  // 32 KiB
    {
        const float4* Wv = reinterpret_cast<const float4*>(W1);
        float4* Lv = reinterpret_cast<float4*>(Wl);
        for (int i = threadIdx.x; i < FIN * FHID / 4; i += 256) Lv[i] = Wv[i];
    }
    __syncthreads();

    int row = blockIdx.x * 256 + threadIdx.x;
    int r = row < n ? row : 0;
    const float4* xr = reinterpret_cast<const float4*>(x + (size_t)r * FIN);

    float acc[FHID];
#pragma unroll
    for (int o = 0; o < FHID; ++o) acc[o] = 0.0f;

#pragma unroll 1
    for (int kt = 0; kt < FIN / 32; ++kt) {
        float4 xv[8];
#pragma unroll
        for (int j = 0; j < 8; ++j) xv[j] = xr[kt * 8 + j];
#pragma unroll
        for (int j = 0; j < 8; ++j) {
#pragma unroll
            for (int q = 0; q < 4; ++q) {
                float xs = (&xv[j].x)[q];
                const float* wrow = &Wl[(kt * 32 + j * 4 + q) * FHID];
#pragma unroll
                for (int o = 0; o < FHID; ++o) acc[o] = fmaf(xs, wrow[o], acc[o]);
            }
        }
    }

    if (row < n) {
        float dv = dinv[row];
        __half2* gp = reinterpret_cast<__half2*>(g + (size_t)row * FHID);
#pragma unroll
        for (int q = 0; q < FHID / 2; ++q)
            gp[q] = __floats2half2_rn(acc[2 * q] * dv, acc[2 * q + 1] * dv);
    }
}

// ---------------- bucket aggregate (+ fused epilogues) ----------------
// LAYER 1: p = fp16(relu(sum*dinv + b1) * dinv)
// LAYER 2: out = log_softmax((sum*dinv) @ W2 + b2)

template <int LAYER>
__global__ __launch_bounds__(256) void k_agg(const int* __restrict__ boff,
                                             const unsigned* __restrict__ sorted,
                                             const __half* __restrict__ gin,
                                             const float* __restrict__ dinv,
                                             const float* __restrict__ b1,
                                             __half* __restrict__ gout,
                                             const float* __restrict__ W2,
                                             const float* __restrict__ b2,
                                             float* __restrict__ out,
                                             int n, int sb) {
    __shared__ float acc4[4][32 * FHID];  // 8 KiB, wave-private copies
    __shared__ float Wl[FHID * FOUT];
    __shared__ float bl[FOUT];

    int b = blockIdx.x;
    int base = b << 5;
    int t = threadIdx.x;
    int w = t >> 6, lane = t & 63, eg = lane >> 4, c = lane & 15;

    for (int i = t; i < 4 * 32 * FHID; i += 256) ((float*)acc4)[i] = 0.0f;
    if (LAYER == 2) {
        for (int i = t; i < FHID * FOUT; i += 256) Wl[i] = W2[i];
        if (t < FOUT) bl[t] = b2[t];
    }
    __syncthreads();

    float* acc = acc4[w];
    unsigned smask = (1u << sb) - 1u;
    int beg = boff[b], end = boff[b + 1];
    int i = beg + (w * 4 + eg);

    // 8-deep software pipeline: 8 sorted loads -> 8 gathers -> 8 LDS atomics
    for (; i + 16 * 7 < end; i += 16 * 8) {
        unsigned sv[8];
#pragma unroll
        for (int k = 0; k < 8; ++k) sv[k] = sorted[i + 16 * k];
        float v[8];
#pragma unroll
        for (int k = 0; k < 8; ++k)
            v[k] = __half2float(gin[((size_t)(sv[k] & smask) << 4) + c]);
#pragma unroll
        for (int k = 0; k < 8; ++k)
            atomicAdd(&acc[((sv[k] >> sb) << 4) + c], v[k]);
    }
    for (; i < end; i += 16) {
        unsigned sv = sorted[i];
        atomicAdd(&acc[((sv >> sb) << 4) + c],
                  __half2float(gin[((size_t)(sv & smask) << 4) + c]));
    }
    __syncthreads();

    if (LAYER == 1) {
        for (int i2 = t; i2 < 32 * FHID; i2 += 256) {
            int nd = base + (i2 >> 4);
            if (nd < n) {
                float s = acc4[0][i2] + acc4[1][i2] + acc4[2][i2] + acc4[3][i2]
                        + __half2float(gin[((size_t)nd << 4) + (i2 & 15)]);
                float dv = dinv[nd];
                float v = fmaxf(fmaf(s, dv, b1[i2 & 15]), 0.0f) * dv;
                gout[((size_t)nd << 4) + (i2 & 15)] = __float2half(v);
            }
        }
    } else {
        // q = sum*dinv into acc4[0]
        for (int i2 = t; i2 < 32 * FHID; i2 += 256) {
            int nd = base + (i2 >> 4);
            float s = acc4[0][i2] + acc4[1][i2] + acc4[2][i2] + acc4[3][i2];
            if (nd < n) {
                s += __half2float(gin[((size_t)nd << 4) + (i2 & 15)]);
                s *= dinv[nd];
            } else s = 0.0f;
            acc4[0][i2] = s;
        }
        __syncthreads();

        // 8 threads per node, 5 outputs each
        int nd = base + (t >> 3);
        int o0 = t & 7;
        if (nd < n) {
            const float* qp = &acc4[0][(t >> 3) << 4];
            float av[5];
#pragma unroll
            for (int j = 0; j < 5; ++j) av[j] = bl[o0 + 8 * j];
#pragma unroll
            for (int k = 0; k < FHID; ++k) {
                float qk = qp[k];
#pragma unroll
                for (int j = 0; j < 5; ++j)
                    av[j] = fmaf(qk, Wl[k * FOUT + o0 + 8 * j], av[j]);
            }
            float m = av[0];
#pragma unroll
            for (int j = 1; j < 5; ++j) m = fmaxf(m, av[j]);
            m = fmaxf(m, __shfl_xor(m, 1));
            m = fmaxf(m, __shfl_xor(m, 2));
            m = fmaxf(m, __shfl_xor(m, 4));
            float ss = 0.0f;
#pragma unroll
            for (int j = 0; j < 5; ++j) ss += expf(av[j] - m);
            ss += __shfl_xor(ss, 1);
            ss += __shfl_xor(ss, 2);
            ss += __shfl_xor(ss, 4);
            float lse = m + logf(ss);
#pragma unroll
            for (int j = 0; j < 5; ++j)
                out[(size_t)nd * FOUT + o0 + 8 * j] = av[j] - lse;
        }
    }
}

// ---------------- launch ----------------

extern "C" void kernel_launch(void* const* d_in, const int* in_sizes, int n_in,
                              void* d_out, int out_size, void* d_ws, size_t ws_size,
                              hipStream_t stream) {
    const float* x  = (const float*)d_in[0];
    const int*   ei = (const int*)d_in[1];
    const float* W1 = (const float*)d_in[2];
    const float* b1 = (const float*)d_in[3];
    const float* W2 = (const float*)d_in[4];
    const float* b2 = (const float*)d_in[5];

    const int fh = in_sizes[3];              // 16
    const int fi = in_sizes[2] / fh;         // 512
    const int n  = in_sizes[0] / fi;         // 100000
    const int E  = in_sizes[1] / 2;          // 3200000
    (void)n_in; (void)out_size; (void)ws_size;

    const int* src = ei;
    const int* dst = ei + E;

    int sb = 32 - __builtin_clz((unsigned)(n - 1));  // bits for src id
    const int NB = (n + 31) >> 5;

    char* w = (char*)d_ws;
    unsigned* sorted = (unsigned*)w;   w += (size_t)E * 4;
    int*   cnt       = (int*)w;        w += (size_t)n * 4;
    int*   bcnt      = (int*)w;        w += (size_t)NBMAX * 4;
    int*   boff      = (int*)w;        w += (size_t)NBMAX * 4;
    int*   cursor    = (int*)w;        w += (size_t)NBMAX * 4;
    float* dinv      = (float*)w;      w += (size_t)n * 4;
    __half* g        = (__half*)w;     w += (size_t)n * FHID * 2;
    __half* p        = (__half*)w;

    float* out = (float*)d_out;

    const int TB = 256;
    const int nb_e = (E + TB - 1) / TB;

    hipMemsetAsync(cnt, 0, (size_t)n * 4, stream);
    k_count<<<nb_e, TB, 0, stream>>>(dst, cnt, E);
    k_bsum<<<NBMAX / TB, TB, 0, stream>>>(cnt, bcnt, dinv, n, NB);
    k_scan1<<<1, 1024, 0, stream>>>(bcnt, boff, cursor);
    k_fill<<<nb_e, TB, 0, stream>>>(src, dst, cursor, sorted, E, sb);

    k_gemm1<<<(n + 255) / 256, 256, 0, stream>>>(x, W1, dinv, g, n);
    k_agg<1><<<NB, TB, 0, stream>>>(boff, sorted, g, dinv, b1, p, W2, b2, out, n, sb);
    k_agg<2><<<NB, TB, 0, stream>>>(boff, sorted, p, dinv, b1, g, W2, b2, out, n, sb);
}